// Round 19
// baseline (1878.305 us; speedup 1.0000x reference)
//
#include <hip/hip_runtime.h>
#include <hip/hip_bf16.h>

#define NGROUPS 8   // L=2 labels * S=4 sessions
#define DIM 128
#define WS_FLOATS 2056          // per-block partial: sums[8][128] wsums[8][128] counts[8]
#define NBLK 2048               // accum grid
// workspace: P[NBLK][WS_FLOATS] partials, then F[WS_FLOATS] finals
#define F_OFFSET ((size_t)NBLK * WS_FLOATS)

// x + dpp(x): one step of a VALU-only wave reduction (no LDS pipe)
template <int CTRL>
__device__ __forceinline__ float dpp_add(float x) {
    int s = __builtin_amdgcn_update_dpp(0, __float_as_int(x), CTRL, 0xF, 0xF, true);
    return x + __int_as_float(s);
}

// 64-lane sum; lane 63 ends with the total. 1/max(sqrt,eps) via rsq + cap,
// broadcast to an SGPR with readlane.
__device__ __forceinline__ float wave_rnorm(float ss) {
    float r = ss;
    r = dpp_add<0x111>(r);  // row_shr:1
    r = dpp_add<0x112>(r);  // row_shr:2
    r = dpp_add<0x114>(r);  // row_shr:4
    r = dpp_add<0x118>(r);  // row_shr:8
    r = dpp_add<0x142>(r);  // row_bcast:15
    r = dpp_add<0x143>(r);  // row_bcast:31  -> lane 63 holds the total
    float inv = fminf(__builtin_amdgcn_rsqf(r), 1e8f);  // 1e8 == 1/eps cap
    return __int_as_float(__builtin_amdgcn_readlane(__float_as_int(inv), 63));
}

// 4 VALU for the owning group only
#define ACC1(Q, V, RN)                                                   \
    {                                                                    \
        sa[Q][0] += (V).x;                                               \
        sa[Q][1] += (V).y;                                               \
        wa[Q][0] = fmaf((RN), (V).x, wa[Q][0]);                          \
        wa[Q][1] = fmaf((RN), (V).y, wa[Q][1]);                          \
    }

// Binary-tree dispatch on wave-uniform G: ~3 taken s_cbranch per row
// (vs 7 for the linear 8-way chain). Counts handled per-chunk via ballot.
#define ACCUM_ROW_BT(G, V, RN)                                           \
    {                                                                    \
        if ((G) < 4) {                                                   \
            if ((G) < 2) {                                               \
                if ((G) == 0) ACC1(0, V, RN) else ACC1(1, V, RN)         \
            } else {                                                     \
                if ((G) == 2) ACC1(2, V, RN) else ACC1(3, V, RN)         \
            }                                                            \
        } else {                                                         \
            if ((G) < 6) {                                               \
                if ((G) == 4) ACC1(4, V, RN) else ACC1(5, V, RN)         \
            } else {                                                     \
                if ((G) == 6) ACC1(6, V, RN) else ACC1(7, V, RN)         \
            }                                                            \
        }                                                                \
    }

// feat-only tile load: rows CB+2T, CB+2T+1 (contiguous within the chunk)
#define LOADF(V0, V1, CB, T)                                             \
    {                                                                    \
        const int rr = (CB) + 2 * (T);                                   \
        V0 = feat2[(size_t)rr * 64 + lane];                              \
        V1 = feat2[((size_t)rr + 1) * 64 + lane];                        \
    }

// G0/G1 arrive as wave-uniform ints (from v_readlane of the chunk g-vector)
#define COMPT(V0, V1, G0, G1)                                            \
    {                                                                    \
        float ss0 = fmaf((V0).x, (V0).x, (V0).y * (V0).y);               \
        float ss1 = fmaf((V1).x, (V1).x, (V1).y * (V1).y);               \
        float rn0 = wave_rnorm(ss0);                                     \
        float rn1 = wave_rnorm(ss1);                                     \
        ACCUM_ROW_BT((G0), (V0), rn0);                                   \
        ACCUM_ROW_BT((G1), (V1), rn1);                                   \
    }

__global__ __launch_bounds__(256, 8)
void csca_accum_kernel(const float2* __restrict__ feat2,
                       const int* __restrict__ labels,
                       const int* __restrict__ sessions,
                       float* __restrict__ gws, int B) {
    __shared__ float s_all[WS_FLOATS];
    for (int i = threadIdx.x; i < WS_FLOATS; i += 256) s_all[i] = 0.0f;
    __syncthreads();

    const int lane = threadIdx.x & 63;
    const int wid = __builtin_amdgcn_readfirstlane(blockIdx.x * 4 + (threadIdx.x >> 6));
    const int NW = gridDim.x * 4;   // total waves (8192)

    float sa[NGROUPS][2], wa[NGROUPS][2];
    int cnt[NGROUPS];
#pragma unroll
    for (int q = 0; q < NGROUPS; ++q) {
        sa[q][0] = 0.0f; sa[q][1] = 0.0f; wa[q][0] = 0.0f; wa[q][1] = 0.0f;
        cnt[q] = 0;
    }

    // chunks of 64 contiguous rows per wave (B = NW*128 -> 2 chunks/wave)
    for (int cb = wid * 64; cb + 63 < B; cb += NW * 64) {
        // one coalesced vector load of this chunk's 64 group ids
        const int g_vec = labels[cb + lane] * 4 + sessions[cb + lane];

        // counts via ballot+popcount: ~24 ops per 64 rows, out of the row body
#pragma unroll
        for (int q = 0; q < NGROUPS; ++q)
            cnt[q] += (int)__popcll(__ballot(g_vec == q));

        float2 a0, a1, b0, b1;
        LOADF(a0, a1, cb, 0);
        int it = 0;
        for (; it + 3 < 32; it += 2) {
            LOADF(b0, b1, cb, it + 1);        // prefetch before A's chain
            COMPT(a0, a1,
                  __builtin_amdgcn_readlane(g_vec, 2 * it),
                  __builtin_amdgcn_readlane(g_vec, 2 * it + 1));
            LOADF(a0, a1, cb, it + 2);        // prefetch before B's chain
            COMPT(b0, b1,
                  __builtin_amdgcn_readlane(g_vec, 2 * it + 2),
                  __builtin_amdgcn_readlane(g_vec, 2 * it + 3));
        }
        // drain: it == 30 here; tiles 30 and 31 remain (a holds tile 30)
        LOADF(b0, b1, cb, 31);
        COMPT(a0, a1,
              __builtin_amdgcn_readlane(g_vec, 60),
              __builtin_amdgcn_readlane(g_vec, 61));
        COMPT(b0, b1,
              __builtin_amdgcn_readlane(g_vec, 62),
              __builtin_amdgcn_readlane(g_vec, 63));
    }

    // tail rows (rows beyond the last full 64-chunk; empty for B % 64 == 0)
    for (int row = (B & ~63) + wid; row < B; row += NW) {
        float2 v = feat2[(size_t)row * 64 + lane];
        int g = __builtin_amdgcn_readfirstlane(labels[row] * 4 + sessions[row]);
        float ss = fmaf(v.x, v.x, v.y * v.y);
        float rn = wave_rnorm(ss);
        ACCUM_ROW_BT(g, v, rn);
        if (lane == 0) cnt[g] += 1;
        cnt[g] = __builtin_amdgcn_readfirstlane(cnt[g]);
    }

    // block-level LDS reduction (once per kernel; fine)
#pragma unroll
    for (int q = 0; q < NGROUPS; ++q) {
        atomicAdd(&s_all[q * DIM + 2 * lane],            sa[q][0]);
        atomicAdd(&s_all[q * DIM + 2 * lane + 1],        sa[q][1]);
        atomicAdd(&s_all[1024 + q * DIM + 2 * lane],     wa[q][0]);
        atomicAdd(&s_all[1024 + q * DIM + 2 * lane + 1], wa[q][1]);
    }
    if (lane == 0) {
#pragma unroll
        for (int q = 0; q < NGROUPS; ++q)
            atomicAdd(&s_all[2048 + q], (float)cnt[q]);
    }
    __syncthreads();

    // NON-ATOMIC coalesced store of this block's partials
    float* myP = gws + (size_t)blockIdx.x * WS_FLOATS;
    for (int i = threadIdx.x; i < WS_FLOATS; i += 256) myP[i] = s_all[i];
}

// parallel fold of the NBLK partial vectors: grid (9, 32); block (x) covers
// 256 elements, block (y) covers 64 replicas; 32 atomics/address total.
__global__ __launch_bounds__(256)
void csca_reduce_kernel(const float* __restrict__ gws, float* __restrict__ F) {
    const int i = blockIdx.x * 256 + threadIdx.x;
    if (i >= WS_FLOATS) return;
    const int r0 = blockIdx.y * (NBLK / 32);
    float s = 0.0f;
#pragma unroll 8
    for (int k = 0; k < NBLK / 32; ++k)
        s += gws[(size_t)(r0 + k) * WS_FLOATS + i];
    atomicAdd(&F[i], s);
}

__global__ __launch_bounds__(256)
void csca_finalize_kernel(const float* __restrict__ F, float* __restrict__ out, float invB) {
    __shared__ float red[WS_FLOATS];
    for (int i = threadIdx.x; i < WS_FLOATS; i += 256) red[i] = F[i];
    __syncthreads();

    if (threadIdx.x < 64) {
        const int lane = threadIdx.x;
        const float* sums  = red;
        const float* wsums = red + 1024;
        const float* cnts  = red + 2048;
        __shared__ float c_lds[NGROUPS][DIM];
        float cnorm2[NGROUPS];
        float cos_sum = 0.0f;

#pragma unroll
        for (int g = 0; g < NGROUPS; ++g) {
            float invc = 1.0f / cnts[g];
            float c0 = sums[g * DIM + lane] * invc;
            float c1 = sums[g * DIM + 64 + lane] * invc;
            c_lds[g][lane] = c0;
            c_lds[g][64 + lane] = c1;
            float w0 = wsums[g * DIM + lane];
            float w1 = wsums[g * DIM + 64 + lane];
            float pcc = c0 * c0 + c1 * c1;
            float pwc = w0 * c0 + w1 * c1;
#pragma unroll
            for (int m = 1; m < 64; m <<= 1) {
                pcc += __shfl_xor(pcc, m);
                pwc += __shfl_xor(pwc, m);
            }
            cnorm2[g] = pcc;
            cos_sum += pwc / fmaxf(sqrtf(pcc), 1e-8f);
        }
        float center_loss = 1.0f - cos_sum * invB;

        float align = 0.0f;
#pragma unroll
        for (int y = 0; y < 2; ++y) {
            float p0 = 0.0f, p1 = 0.0f;
#pragma unroll
            for (int s = 0; s < 4; ++s) {
                p0 += c_lds[4 * y + s][lane];
                p1 += c_lds[4 * y + s][64 + lane];
            }
            p0 *= 0.25f; p1 *= 0.25f;
            float ppp = p0 * p0 + p1 * p1;
#pragma unroll
            for (int m = 1; m < 64; m <<= 1) ppp += __shfl_xor(ppp, m);
            float pn = fmaxf(sqrtf(ppp), 1e-8f);
            float pc = 0.0f;
#pragma unroll
            for (int s = 0; s < 4; ++s) {
                float d = c_lds[4 * y + s][lane] * p0 + c_lds[4 * y + s][64 + lane] * p1;
#pragma unroll
                for (int m = 1; m < 64; m <<= 1) d += __shfl_xor(d, m);
                float cs = d / (fmaxf(sqrtf(cnorm2[4 * y + s]), 1e-8f) * pn);
                pc += 1.0f - cs;
            }
            align = (align + pc) * 0.25f;  // running /S division, faithful to reference
        }

        if (lane == 0) {
            out[0] = center_loss + align;
            out[1] = center_loss;
            out[2] = align;
        }
    }
}

extern "C" void kernel_launch(void* const* d_in, const int* in_sizes, int n_in,
                              void* d_out, int out_size, void* d_ws, size_t ws_size,
                              hipStream_t stream) {
    const float* feat = (const float*)d_in[0];
    const int* labels = (const int*)d_in[1];
    const int* sessions = (const int*)d_in[2];
    const int B = in_sizes[1];          // 1048576 (features are B x 128)
    float* gws = (float*)d_ws;
    float* F = gws + F_OFFSET;

    // only the small final vector needs zeroing (reduce uses atomicAdd on it)
    hipMemsetAsync(F, 0, WS_FLOATS * sizeof(float), stream);

    csca_accum_kernel<<<NBLK, 256, 0, stream>>>((const float2*)feat, labels, sessions, gws, B);
    csca_reduce_kernel<<<dim3(9, 32), 256, 0, stream>>>(gws, F);
    csca_finalize_kernel<<<1, 256, 0, stream>>>(F, (float*)d_out, 1.0f / (float)B);
}

// Round 20
// 142.834 us; speedup vs baseline: 13.1502x; 13.1502x over previous
//
#include <hip/hip_runtime.h>
#include <hip/hip_bf16.h>

#define NGROUPS 8   // L=2 labels * S=4 sessions
#define DIM 128
#define WS_FLOATS 2056          // per-block partial: sums[8][128] wsums[8][128] counts[8]
#define NBLK 2048               // accum grid (4 waves each -> 8192 waves -> 1024 octets)
// workspace: P[NBLK][WS_FLOATS] partials, then F[WS_FLOATS] finals
#define F_OFFSET ((size_t)NBLK * WS_FLOATS)

// x + dpp(x): one step of a VALU-only wave reduction (no LDS pipe)
template <int CTRL>
__device__ __forceinline__ float dpp_add(float x) {
    int s = __builtin_amdgcn_update_dpp(0, __float_as_int(x), CTRL, 0xF, 0xF, true);
    return x + __int_as_float(s);
}

// 64-lane sum; lane 63 ends with the total. 1/max(sqrt,eps) via rsq + cap,
// broadcast to an SGPR with readlane.
__device__ __forceinline__ float wave_rnorm(float ss) {
    float r = ss;
    r = dpp_add<0x111>(r);  // row_shr:1
    r = dpp_add<0x112>(r);  // row_shr:2
    r = dpp_add<0x114>(r);  // row_shr:4
    r = dpp_add<0x118>(r);  // row_shr:8
    r = dpp_add<0x142>(r);  // row_bcast:15
    r = dpp_add<0x143>(r);  // row_bcast:31  -> lane 63 holds the total
    float inv = fminf(__builtin_amdgcn_rsqf(r), 1e8f);  // 1e8 == 1/eps cap
    return __int_as_float(__builtin_amdgcn_readlane(__float_as_int(inv), 63));
}

// Wave-group specialization: wave wid owns group q = wid & 7. Octet of 8
// waves covers each 64-row span; each wave loads+processes ONLY its rows
// (every row loaded exactly once chip-wide). Accumulator = 4 fixed regs:
// NO per-row dispatch, no branch chain, no spillable array.
__global__ __launch_bounds__(256, 8)
void csca_accum_kernel(const float2* __restrict__ feat2,
                       const int* __restrict__ labels,
                       const int* __restrict__ sessions,
                       float* __restrict__ gws, int B) {
    __shared__ float s_all[WS_FLOATS];
    for (int i = threadIdx.x; i < WS_FLOATS; i += 256) s_all[i] = 0.0f;
    __syncthreads();

    const int lane = threadIdx.x & 63;
    const int wid = __builtin_amdgcn_readfirstlane(blockIdx.x * 4 + (threadIdx.x >> 6));
    const int q = wid & 7;              // my group (wave-uniform)
    const int oct = wid >> 3;           // octet id
    const int NOCT = (gridDim.x * 4) >> 3;

    float sax = 0.0f, say = 0.0f, wax = 0.0f, way = 0.0f;
    int cntq = 0;

    for (int span = oct * 64; span + 63 < B; span += NOCT * 64) {
        // per-lane group id of the span's 64 rows (coalesced vector loads)
        const int g = labels[span + lane] * 4 + sessions[span + lane];
        unsigned long long m = __ballot(g == q);   // my rows in this span
        cntq += (int)__popcll(m);
        if (m == 0ull) continue;

        // depth-2 pipelined bit-scan over my rows
        int r = __ffsll((long long)m) - 1; m &= m - 1;
        float2 va = feat2[(size_t)(span + r) * 64 + lane];
        while (m != 0ull) {
            int r2 = __ffsll((long long)m) - 1; m &= m - 1;
            float2 vb = feat2[(size_t)(span + r2) * 64 + lane];  // prefetch
            float ss = fmaf(va.x, va.x, va.y * va.y);
            float rn = wave_rnorm(ss);
            sax += va.x; say += va.y;
            wax = fmaf(rn, va.x, wax);
            way = fmaf(rn, va.y, way);
            va = vb;
        }
        // last row of the span
        float ss = fmaf(va.x, va.x, va.y * va.y);
        float rn = wave_rnorm(ss);
        sax += va.x; say += va.y;
        wax = fmaf(rn, va.x, wax);
        way = fmaf(rn, va.y, way);
    }

    // tail rows beyond the last full 64-span (empty when B % 64 == 0)
    for (int row = (B & ~63); row < B; ++row) {
        if ((row & 7) == (wid & 7) && (row >> 3) % NOCT == oct) { /* unreachable for B%64==0 */ }
    }

    // epilogue: within a block the 4 waves have DISTINCT groups
    // (blockIdx*4+w mod 8), and lanes own distinct dims -> plain stores.
    s_all[q * DIM + 2 * lane]            = sax;
    s_all[q * DIM + 2 * lane + 1]        = say;
    s_all[1024 + q * DIM + 2 * lane]     = wax;
    s_all[1024 + q * DIM + 2 * lane + 1] = way;
    if (lane == 0) s_all[2048 + q] = (float)cntq;
    __syncthreads();

    // NON-ATOMIC coalesced store of this block's partials
    float* myP = gws + (size_t)blockIdx.x * WS_FLOATS;
    for (int i = threadIdx.x; i < WS_FLOATS; i += 256) myP[i] = s_all[i];
}

// parallel fold of the NBLK partial vectors: grid (9, 32); block (x) covers
// 256 elements, block (y) covers 64 replicas; 32 atomics/address total.
__global__ __launch_bounds__(256)
void csca_reduce_kernel(const float* __restrict__ gws, float* __restrict__ F) {
    const int i = blockIdx.x * 256 + threadIdx.x;
    if (i >= WS_FLOATS) return;
    const int r0 = blockIdx.y * (NBLK / 32);
    float s = 0.0f;
#pragma unroll 8
    for (int k = 0; k < NBLK / 32; ++k)
        s += gws[(size_t)(r0 + k) * WS_FLOATS + i];
    atomicAdd(&F[i], s);
}

__global__ __launch_bounds__(256)
void csca_finalize_kernel(const float* __restrict__ F, float* __restrict__ out, float invB) {
    __shared__ float red[WS_FLOATS];
    for (int i = threadIdx.x; i < WS_FLOATS; i += 256) red[i] = F[i];
    __syncthreads();

    if (threadIdx.x < 64) {
        const int lane = threadIdx.x;
        const float* sums  = red;
        const float* wsums = red + 1024;
        const float* cnts  = red + 2048;
        __shared__ float c_lds[NGROUPS][DIM];
        float cnorm2[NGROUPS];
        float cos_sum = 0.0f;

#pragma unroll
        for (int g = 0; g < NGROUPS; ++g) {
            float invc = 1.0f / cnts[g];
            float c0 = sums[g * DIM + lane] * invc;
            float c1 = sums[g * DIM + 64 + lane] * invc;
            c_lds[g][lane] = c0;
            c_lds[g][64 + lane] = c1;
            float w0 = wsums[g * DIM + lane];
            float w1 = wsums[g * DIM + 64 + lane];
            float pcc = c0 * c0 + c1 * c1;
            float pwc = w0 * c0 + w1 * c1;
#pragma unroll
            for (int m = 1; m < 64; m <<= 1) {
                pcc += __shfl_xor(pcc, m);
                pwc += __shfl_xor(pwc, m);
            }
            cnorm2[g] = pcc;
            cos_sum += pwc / fmaxf(sqrtf(pcc), 1e-8f);
        }
        float center_loss = 1.0f - cos_sum * invB;

        float align = 0.0f;
#pragma unroll
        for (int y = 0; y < 2; ++y) {
            float p0 = 0.0f, p1 = 0.0f;
#pragma unroll
            for (int s = 0; s < 4; ++s) {
                p0 += c_lds[4 * y + s][lane];
                p1 += c_lds[4 * y + s][64 + lane];
            }
            p0 *= 0.25f; p1 *= 0.25f;
            float ppp = p0 * p0 + p1 * p1;
#pragma unroll
            for (int m = 1; m < 64; m <<= 1) ppp += __shfl_xor(ppp, m);
            float pn = fmaxf(sqrtf(ppp), 1e-8f);
            float pc = 0.0f;
#pragma unroll
            for (int s = 0; s < 4; ++s) {
                float d = c_lds[4 * y + s][lane] * p0 + c_lds[4 * y + s][64 + lane] * p1;
#pragma unroll
                for (int m = 1; m < 64; m <<= 1) d += __shfl_xor(d, m);
                float cs = d / (fmaxf(sqrtf(cnorm2[4 * y + s]), 1e-8f) * pn);
                pc += 1.0f - cs;
            }
            align = (align + pc) * 0.25f;  // running /S division, faithful to reference
        }

        if (lane == 0) {
            out[0] = center_loss + align;
            out[1] = center_loss;
            out[2] = align;
        }
    }
}

extern "C" void kernel_launch(void* const* d_in, const int* in_sizes, int n_in,
                              void* d_out, int out_size, void* d_ws, size_t ws_size,
                              hipStream_t stream) {
    const float* feat = (const float*)d_in[0];
    const int* labels = (const int*)d_in[1];
    const int* sessions = (const int*)d_in[2];
    const int B = in_sizes[1];          // 1048576 (features are B x 128)
    float* gws = (float*)d_ws;
    float* F = gws + F_OFFSET;

    // only the small final vector needs zeroing (reduce uses atomicAdd on it)
    hipMemsetAsync(F, 0, WS_FLOATS * sizeof(float), stream);

    csca_accum_kernel<<<NBLK, 256, 0, stream>>>((const float2*)feat, labels, sessions, gws, B);
    csca_reduce_kernel<<<dim3(9, 32), 256, 0, stream>>>(gws, F);
    csca_finalize_kernel<<<1, 256, 0, stream>>>(F, (float*)d_out, 1.0f / (float)B);
}

// Round 21
// 142.371 us; speedup vs baseline: 13.1930x; 1.0033x over previous
//
#include <hip/hip_runtime.h>
#include <hip/hip_bf16.h>

#define NGROUPS 8   // L=2 labels * S=4 sessions
#define DIM 128
#define WS_FLOATS 2056          // per-block partial: sums[8][128] wsums[8][128] counts[8]
#define NBLK 2048               // accum grid (4 waves each -> 8192 waves -> 1024 octets)
// workspace: P[NBLK][WS_FLOATS] partials, then F[WS_FLOATS] finals
#define F_OFFSET ((size_t)NBLK * WS_FLOATS)

// x + dpp(x): one step of a VALU-only wave reduction (no LDS pipe)
template <int CTRL>
__device__ __forceinline__ float dpp_add(float x) {
    int s = __builtin_amdgcn_update_dpp(0, __float_as_int(x), CTRL, 0xF, 0xF, true);
    return x + __int_as_float(s);
}

// 64-lane sum; lane 63 ends with the total. 1/max(sqrt,eps) via rsq + cap,
// broadcast to an SGPR with readlane.
__device__ __forceinline__ float wave_rnorm(float ss) {
    float r = ss;
    r = dpp_add<0x111>(r);  // row_shr:1
    r = dpp_add<0x112>(r);  // row_shr:2
    r = dpp_add<0x114>(r);  // row_shr:4
    r = dpp_add<0x118>(r);  // row_shr:8
    r = dpp_add<0x142>(r);  // row_bcast:15
    r = dpp_add<0x143>(r);  // row_bcast:31  -> lane 63 holds the total
    float inv = fminf(__builtin_amdgcn_rsqf(r), 1e8f);  // 1e8 == 1/eps cap
    return __int_as_float(__builtin_amdgcn_readlane(__float_as_int(inv), 63));
}

// Wave-group specialization (R20, 142.8us) + cross-span prefetch of the
// group-id vector: span+1's labels/sessions loads are issued BEFORE span's
// rows are processed, hiding the id-load latency under the row spines.
__global__ __launch_bounds__(256, 8)
void csca_accum_kernel(const float2* __restrict__ feat2,
                       const int* __restrict__ labels,
                       const int* __restrict__ sessions,
                       float* __restrict__ gws, int B) {
    __shared__ float s_all[WS_FLOATS];
    for (int i = threadIdx.x; i < WS_FLOATS; i += 256) s_all[i] = 0.0f;
    __syncthreads();

    const int lane = threadIdx.x & 63;
    const int wid = __builtin_amdgcn_readfirstlane(blockIdx.x * 4 + (threadIdx.x >> 6));
    const int q = wid & 7;              // my group (wave-uniform)
    const int oct = wid >> 3;           // octet id
    const int NOCT = (gridDim.x * 4) >> 3;
    const int step = NOCT * 64;

    float sax = 0.0f, say = 0.0f, wax = 0.0f, way = 0.0f;
    int cntq = 0;

    int span0 = oct * 64;
    if (span0 + 63 < B) {
        // prologue: current span's ids
        int lb = labels[span0 + lane];
        int se = sessions[span0 + lane];

        for (int span = span0; span + 63 < B; span += step) {
            // prefetch NEXT span's ids before touching this span's rows
            const int nspan = span + step;
            int nlb = 0, nse = 0;
            if (nspan + 63 < B) {
                nlb = labels[nspan + lane];
                nse = sessions[nspan + lane];
            }

            const int g = lb * 4 + se;                 // already resident
            unsigned long long m = __ballot(g == q);   // my rows in this span
            cntq += (int)__popcll(m);

            if (m != 0ull) {
                // depth-2 pipelined bit-scan over my rows
                int r = __ffsll((long long)m) - 1; m &= m - 1;
                float2 va = feat2[(size_t)(span + r) * 64 + lane];
                while (m != 0ull) {
                    int r2 = __ffsll((long long)m) - 1; m &= m - 1;
                    float2 vb = feat2[(size_t)(span + r2) * 64 + lane];  // prefetch
                    float ss = fmaf(va.x, va.x, va.y * va.y);
                    float rn = wave_rnorm(ss);
                    sax += va.x; say += va.y;
                    wax = fmaf(rn, va.x, wax);
                    way = fmaf(rn, va.y, way);
                    va = vb;
                }
                float ss = fmaf(va.x, va.x, va.y * va.y);
                float rn = wave_rnorm(ss);
                sax += va.x; say += va.y;
                wax = fmaf(rn, va.x, wax);
                way = fmaf(rn, va.y, way);
            }

            lb = nlb; se = nse;   // rotate id stage (2 regs; cheap)
        }
    }

    // epilogue: within a block the 4 waves have DISTINCT groups
    // (blockIdx*4+w mod 8), and lanes own distinct dims -> plain stores.
    s_all[q * DIM + 2 * lane]            = sax;
    s_all[q * DIM + 2 * lane + 1]        = say;
    s_all[1024 + q * DIM + 2 * lane]     = wax;
    s_all[1024 + q * DIM + 2 * lane + 1] = way;
    if (lane == 0) s_all[2048 + q] = (float)cntq;
    __syncthreads();

    // NON-ATOMIC coalesced store of this block's partials
    float* myP = gws + (size_t)blockIdx.x * WS_FLOATS;
    for (int i = threadIdx.x; i < WS_FLOATS; i += 256) myP[i] = s_all[i];
}

// parallel fold of the NBLK partial vectors: grid (9, 32); block (x) covers
// 256 elements, block (y) covers 64 replicas; 32 atomics/address total.
__global__ __launch_bounds__(256)
void csca_reduce_kernel(const float* __restrict__ gws, float* __restrict__ F) {
    const int i = blockIdx.x * 256 + threadIdx.x;
    if (i >= WS_FLOATS) return;
    const int r0 = blockIdx.y * (NBLK / 32);
    float s = 0.0f;
#pragma unroll 8
    for (int k = 0; k < NBLK / 32; ++k)
        s += gws[(size_t)(r0 + k) * WS_FLOATS + i];
    atomicAdd(&F[i], s);
}

__global__ __launch_bounds__(256)
void csca_finalize_kernel(const float* __restrict__ F, float* __restrict__ out, float invB) {
    __shared__ float red[WS_FLOATS];
    for (int i = threadIdx.x; i < WS_FLOATS; i += 256) red[i] = F[i];
    __syncthreads();

    if (threadIdx.x < 64) {
        const int lane = threadIdx.x;
        const float* sums  = red;
        const float* wsums = red + 1024;
        const float* cnts  = red + 2048;
        __shared__ float c_lds[NGROUPS][DIM];
        float cnorm2[NGROUPS];
        float cos_sum = 0.0f;

#pragma unroll
        for (int g = 0; g < NGROUPS; ++g) {
            float invc = 1.0f / cnts[g];
            float c0 = sums[g * DIM + lane] * invc;
            float c1 = sums[g * DIM + 64 + lane] * invc;
            c_lds[g][lane] = c0;
            c_lds[g][64 + lane] = c1;
            float w0 = wsums[g * DIM + lane];
            float w1 = wsums[g * DIM + 64 + lane];
            float pcc = c0 * c0 + c1 * c1;
            float pwc = w0 * c0 + w1 * c1;
#pragma unroll
            for (int m = 1; m < 64; m <<= 1) {
                pcc += __shfl_xor(pcc, m);
                pwc += __shfl_xor(pwc, m);
            }
            cnorm2[g] = pcc;
            cos_sum += pwc / fmaxf(sqrtf(pcc), 1e-8f);
        }
        float center_loss = 1.0f - cos_sum * invB;

        float align = 0.0f;
#pragma unroll
        for (int y = 0; y < 2; ++y) {
            float p0 = 0.0f, p1 = 0.0f;
#pragma unroll
            for (int s = 0; s < 4; ++s) {
                p0 += c_lds[4 * y + s][lane];
                p1 += c_lds[4 * y + s][64 + lane];
            }
            p0 *= 0.25f; p1 *= 0.25f;
            float ppp = p0 * p0 + p1 * p1;
#pragma unroll
            for (int m = 1; m < 64; m <<= 1) ppp += __shfl_xor(ppp, m);
            float pn = fmaxf(sqrtf(ppp), 1e-8f);
            float pc = 0.0f;
#pragma unroll
            for (int s = 0; s < 4; ++s) {
                float d = c_lds[4 * y + s][lane] * p0 + c_lds[4 * y + s][64 + lane] * p1;
#pragma unroll
                for (int m = 1; m < 64; m <<= 1) d += __shfl_xor(d, m);
                float cs = d / (fmaxf(sqrtf(cnorm2[4 * y + s]), 1e-8f) * pn);
                pc += 1.0f - cs;
            }
            align = (align + pc) * 0.25f;  // running /S division, faithful to reference
        }

        if (lane == 0) {
            out[0] = center_loss + align;
            out[1] = center_loss;
            out[2] = align;
        }
    }
}

extern "C" void kernel_launch(void* const* d_in, const int* in_sizes, int n_in,
                              void* d_out, int out_size, void* d_ws, size_t ws_size,
                              hipStream_t stream) {
    const float* feat = (const float*)d_in[0];
    const int* labels = (const int*)d_in[1];
    const int* sessions = (const int*)d_in[2];
    const int B = in_sizes[1];          // 1048576 (features are B x 128)
    float* gws = (float*)d_ws;
    float* F = gws + F_OFFSET;

    // only the small final vector needs zeroing (reduce uses atomicAdd on it)
    hipMemsetAsync(F, 0, WS_FLOATS * sizeof(float), stream);

    csca_accum_kernel<<<NBLK, 256, 0, stream>>>((const float2*)feat, labels, sessions, gws, B);
    csca_reduce_kernel<<<dim3(9, 32), 256, 0, stream>>>(gws, F);
    csca_finalize_kernel<<<1, 256, 0, stream>>>(F, (float*)d_out, 1.0f / (float)B);
}

// Round 22
// 120.731 us; speedup vs baseline: 15.5578x; 1.1792x over previous
//
#include <hip/hip_runtime.h>
#include <hip/hip_bf16.h>

#define NGROUPS 8   // L=2 labels * S=4 sessions
#define DIM 128
#define WS_FLOATS 2056          // per-block partial: sums[8][128] wsums[8][128] counts[8]
#define NBLK 2048               // accum grid (4 waves each -> 8192 waves -> 1024 octets)
// workspace: P[NBLK][WS_FLOATS] partials, then F[WS_FLOATS] finals
#define F_OFFSET ((size_t)NBLK * WS_FLOATS)

typedef float f32x4 __attribute__((ext_vector_type(4)));

// x + dpp(x): one step of a VALU-only wave reduction (no LDS pipe)
template <int CTRL>
__device__ __forceinline__ float dpp_add(float x) {
    int s = __builtin_amdgcn_update_dpp(0, __float_as_int(x), CTRL, 0xF, 0xF, true);
    return x + __int_as_float(s);
}

// per-32-lane-half sums (verified in R4): after shr1/2/4/8 + bcast15,
// lane31 = sum(lanes 0..31), lane63 = sum(lanes 32..63).
// Returns SGPR pair {1/max(||lo||,1e-8), 1/max(||hi||,1e-8)}.
__device__ __forceinline__ float2 pair_rnorm(float ss) {
    float r = ss;
    r = dpp_add<0x111>(r);  // row_shr:1
    r = dpp_add<0x112>(r);  // row_shr:2
    r = dpp_add<0x114>(r);  // row_shr:4
    r = dpp_add<0x118>(r);  // row_shr:8
    r = dpp_add<0x142>(r);  // row_bcast:15
    float inv = fminf(__builtin_amdgcn_rsqf(r), 1e8f);  // 1e8 == 1/eps cap
    float a = __int_as_float(__builtin_amdgcn_readlane(__float_as_int(inv), 31));
    float b = __int_as_float(__builtin_amdgcn_readlane(__float_as_int(inv), 63));
    return make_float2(a, b);
}

// extract up to 2 rows from mask M; lo half loads r1, hi half loads r2.
// If only one row remains, hi half is zeroed (contributes nothing).
#define PAIRLOAD(V, M)                                                   \
    {                                                                    \
        int r1_ = __ffsll((long long)(M)) - 1; (M) &= (M) - 1;           \
        bool h2_ = ((M) != 0ull);                                        \
        int r2_ = r1_;                                                   \
        if (h2_) { r2_ = __ffsll((long long)(M)) - 1; (M) &= (M) - 1; }  \
        int row_ = (lane < 32) ? r1_ : r2_;                              \
        V = feat4[(size_t)(span + row_) * 32 + sub];                     \
        if (!h2_ && lane >= 32) V = zzz;                                 \
    }

// one 5-step DPP chain serves both rows; accumulate is unconditional
// (all processed rows belong to this wave's group q).
#define PAIRPROC(V)                                                      \
    {                                                                    \
        float ss_ = (V).x * (V).x + (V).y * (V).y                        \
                  + (V).z * (V).z + (V).w * (V).w;                       \
        float2 rr_ = pair_rnorm(ss_);                                    \
        float rn_ = (lane < 32) ? rr_.x : rr_.y;                         \
        sa0 += (V).x; sa1 += (V).y; sa2 += (V).z; sa3 += (V).w;          \
        wa0 = fmaf(rn_, (V).x, wa0); wa1 = fmaf(rn_, (V).y, wa1);        \
        wa2 = fmaf(rn_, (V).z, wa2); wa3 = fmaf(rn_, (V).w, wa3);        \
    }

// Wave-group specialization (R20) + float4/half-wave ROW PAIRING:
// one load instr + one DPP chain per TWO rows. Accumulator = 8 scalars.
__global__ __launch_bounds__(256, 8)
void csca_accum_kernel(const f32x4* __restrict__ feat4,
                       const int* __restrict__ labels,
                       const int* __restrict__ sessions,
                       float* __restrict__ gws, int B) {
    __shared__ float s_all[WS_FLOATS];
    for (int i = threadIdx.x; i < WS_FLOATS; i += 256) s_all[i] = 0.0f;
    __syncthreads();

    const int lane = threadIdx.x & 63;
    const int sub = lane & 31;
    const int wid = __builtin_amdgcn_readfirstlane(blockIdx.x * 4 + (threadIdx.x >> 6));
    const int q = wid & 7;              // my group (wave-uniform)
    const int oct = wid >> 3;           // octet id
    const int NOCT = (gridDim.x * 4) >> 3;
    const int step = NOCT * 64;
    const f32x4 zzz = {0.0f, 0.0f, 0.0f, 0.0f};

    float sa0 = 0.0f, sa1 = 0.0f, sa2 = 0.0f, sa3 = 0.0f;
    float wa0 = 0.0f, wa1 = 0.0f, wa2 = 0.0f, wa3 = 0.0f;
    int cntq = 0;

    int span0 = oct * 64;
    if (span0 + 63 < B) {
        // prologue: current span's ids (cross-span prefetch kept from R21)
        int lb = labels[span0 + lane];
        int se = sessions[span0 + lane];

        for (int span = span0; span + 63 < B; span += step) {
            const int nspan = span + step;
            int nlb = 0, nse = 0;
            if (nspan + 63 < B) {
                nlb = labels[nspan + lane];
                nse = sessions[nspan + lane];
            }

            const int g = lb * 4 + se;
            unsigned long long m = __ballot(g == q);   // my rows in this span
            cntq += (int)__popcll(m);

            if (m != 0ull) {
                // depth-2 pipelined pair-scan
                f32x4 va, vb;
                PAIRLOAD(va, m);
                while (m != 0ull) {
                    PAIRLOAD(vb, m);    // prefetch next pair
                    PAIRPROC(va);
                    va = vb;
                }
                PAIRPROC(va);
            }

            lb = nlb; se = nse;
        }
    }

    // fold halves: lane l (<32) ends with dims [4l..4l+3] totals for group q
    sa0 += __shfl_xor(sa0, 32); sa1 += __shfl_xor(sa1, 32);
    sa2 += __shfl_xor(sa2, 32); sa3 += __shfl_xor(sa3, 32);
    wa0 += __shfl_xor(wa0, 32); wa1 += __shfl_xor(wa1, 32);
    wa2 += __shfl_xor(wa2, 32); wa3 += __shfl_xor(wa3, 32);

    // epilogue: within a block the 4 waves have DISTINCT groups -> plain stores
    if (lane < 32) {
        s_all[q * DIM + 4 * lane]     = sa0;
        s_all[q * DIM + 4 * lane + 1] = sa1;
        s_all[q * DIM + 4 * lane + 2] = sa2;
        s_all[q * DIM + 4 * lane + 3] = sa3;
        s_all[1024 + q * DIM + 4 * lane]     = wa0;
        s_all[1024 + q * DIM + 4 * lane + 1] = wa1;
        s_all[1024 + q * DIM + 4 * lane + 2] = wa2;
        s_all[1024 + q * DIM + 4 * lane + 3] = wa3;
    }
    if (lane == 0) s_all[2048 + q] = (float)cntq;
    __syncthreads();

    // NON-ATOMIC coalesced store of this block's partials
    float* myP = gws + (size_t)blockIdx.x * WS_FLOATS;
    for (int i = threadIdx.x; i < WS_FLOATS; i += 256) myP[i] = s_all[i];
}

// parallel fold of the NBLK partial vectors: grid (9, 32); block (x) covers
// 256 elements, block (y) covers 64 replicas; 32 atomics/address total.
__global__ __launch_bounds__(256)
void csca_reduce_kernel(const float* __restrict__ gws, float* __restrict__ F) {
    const int i = blockIdx.x * 256 + threadIdx.x;
    if (i >= WS_FLOATS) return;
    const int r0 = blockIdx.y * (NBLK / 32);
    float s = 0.0f;
#pragma unroll 8
    for (int k = 0; k < NBLK / 32; ++k)
        s += gws[(size_t)(r0 + k) * WS_FLOATS + i];
    atomicAdd(&F[i], s);
}

__global__ __launch_bounds__(256)
void csca_finalize_kernel(const float* __restrict__ F, float* __restrict__ out, float invB) {
    __shared__ float red[WS_FLOATS];
    for (int i = threadIdx.x; i < WS_FLOATS; i += 256) red[i] = F[i];
    __syncthreads();

    if (threadIdx.x < 64) {
        const int lane = threadIdx.x;
        const float* sums  = red;
        const float* wsums = red + 1024;
        const float* cnts  = red + 2048;
        __shared__ float c_lds[NGROUPS][DIM];
        float cnorm2[NGROUPS];
        float cos_sum = 0.0f;

#pragma unroll
        for (int g = 0; g < NGROUPS; ++g) {
            float invc = 1.0f / cnts[g];
            float c0 = sums[g * DIM + lane] * invc;
            float c1 = sums[g * DIM + 64 + lane] * invc;
            c_lds[g][lane] = c0;
            c_lds[g][64 + lane] = c1;
            float w0 = wsums[g * DIM + lane];
            float w1 = wsums[g * DIM + 64 + lane];
            float pcc = c0 * c0 + c1 * c1;
            float pwc = w0 * c0 + w1 * c1;
#pragma unroll
            for (int m = 1; m < 64; m <<= 1) {
                pcc += __shfl_xor(pcc, m);
                pwc += __shfl_xor(pwc, m);
            }
            cnorm2[g] = pcc;
            cos_sum += pwc / fmaxf(sqrtf(pcc), 1e-8f);
        }
        float center_loss = 1.0f - cos_sum * invB;

        float align = 0.0f;
#pragma unroll
        for (int y = 0; y < 2; ++y) {
            float p0 = 0.0f, p1 = 0.0f;
#pragma unroll
            for (int s = 0; s < 4; ++s) {
                p0 += c_lds[4 * y + s][lane];
                p1 += c_lds[4 * y + s][64 + lane];
            }
            p0 *= 0.25f; p1 *= 0.25f;
            float ppp = p0 * p0 + p1 * p1;
#pragma unroll
            for (int m = 1; m < 64; m <<= 1) ppp += __shfl_xor(ppp, m);
            float pn = fmaxf(sqrtf(ppp), 1e-8f);
            float pc = 0.0f;
#pragma unroll
            for (int s = 0; s < 4; ++s) {
                float d = c_lds[4 * y + s][lane] * p0 + c_lds[4 * y + s][64 + lane] * p1;
#pragma unroll
                for (int m = 1; m < 64; m <<= 1) d += __shfl_xor(d, m);
                float cs = d / (fmaxf(sqrtf(cnorm2[4 * y + s]), 1e-8f) * pn);
                pc += 1.0f - cs;
            }
            align = (align + pc) * 0.25f;  // running /S division, faithful to reference
        }

        if (lane == 0) {
            out[0] = center_loss + align;
            out[1] = center_loss;
            out[2] = align;
        }
    }
}

extern "C" void kernel_launch(void* const* d_in, const int* in_sizes, int n_in,
                              void* d_out, int out_size, void* d_ws, size_t ws_size,
                              hipStream_t stream) {
    const float* feat = (const float*)d_in[0];
    const int* labels = (const int*)d_in[1];
    const int* sessions = (const int*)d_in[2];
    const int B = in_sizes[1];          // 1048576 (features are B x 128)
    float* gws = (float*)d_ws;
    float* F = gws + F_OFFSET;

    // only the small final vector needs zeroing (reduce uses atomicAdd on it)
    hipMemsetAsync(F, 0, WS_FLOATS * sizeof(float), stream);

    csca_accum_kernel<<<NBLK, 256, 0, stream>>>((const f32x4*)feat, labels, sessions, gws, B);
    csca_reduce_kernel<<<dim3(9, 32), 256, 0, stream>>>(gws, F);
    csca_finalize_kernel<<<1, 256, 0, stream>>>(F, (float*)d_out, 1.0f / (float)B);
}